// Round 12
// baseline (410.650 us; speedup 1.0000x reference)
//
#include <hip/hip_runtime.h>
#include <hip/hip_fp16.h>
#include <math.h>

#define N_NODES 50000
#define N_EDGES 1200000
#define N_GRAPHS 128
#define D_IN 32
#define D_H 64
#define D_OUT 10
#define ELL_CAP 64
#define EQ (N_EDGES / 4)          // 300000, edges per ILP slot

#define EPS 1e-7f
#define MAX_NORM (1.0f - 1e-5f)

typedef _Float16 half8 __attribute__((ext_vector_type(8)));
typedef float float4v __attribute__((ext_vector_type(4)));

// ---------------- wave helpers ----------------

__device__ __forceinline__ float wave_reduce_sum(float v) {
    #pragma unroll
    for (int off = 32; off > 0; off >>= 1)
        v += __shfl_xor(v, off, 64);
    return v;
}

// sum over the 32 lanes of each half (halves hold identical data -> both
// halves end with the full sum)
__device__ __forceinline__ float reduce32(float v) {
    #pragma unroll
    for (int off = 16; off > 0; off >>= 1)
        v += __shfl_xor(v, off, 64);
    return v;
}

// logmap0(proj(expmap0(u))) on a 64-lane-distributed vector.
__device__ __forceinline__ float exp_proj_log(float m) {
    float n = fmaxf(sqrtf(wave_reduce_sum(m * m)), EPS);
    float v = tanhf(n) * m / n;
    float nv = fmaxf(sqrtf(wave_reduce_sum(v * v)), EPS);
    if (nv > MAX_NORM) v = v * (MAX_NORM / nv);
    float nl = sqrtf(wave_reduce_sum(v * v));
    nl = fminf(fmaxf(nl, EPS), MAX_NORM);
    return atanhf(nl) * v / nl;
}

// ---------------- kernels ----------------

// Fused: [blocks 0..EB) ELL build, 4 independent edges per thread; [EB..)
// tangent0 = fp16(logmap0(proj(expmap0(x)))).
// R12: ELL entry stored via NON-RETURNING atomicOr into a packed u32 word.
// Device-scope atomics execute at the coherent point and write through
// exactly their payload (measured R1: WRITE_SIZE == atomic payload) — no
// 64B line write-allocate ping-pong across non-coherent XCD L2s (the 72MB
// WRITE_SIZE / ~117us cost of the plain-store version). Requires ell
// pre-zeroed (leading memset covers it). XCD-safe by construction, unlike
// R10's partitioned build.
#define EB ((EQ + 255) / 256)
__global__ void build_kernel(const int* __restrict__ src, const int* __restrict__ dst,
                             int* __restrict__ deg, unsigned int* __restrict__ ell32,
                             const float* __restrict__ x, __half* __restrict__ u0) {
    if (blockIdx.x < EB) {
        int tid = blockIdx.x * 256 + threadIdx.x;
        if (tid < EQ) {
            #pragma unroll
            for (int q = 0; q < 4; ++q) {
                int e = tid + q * EQ;
                int s = src[e];
                int d = dst[e];
                s = min(max(s, 0), N_NODES - 1);
                d = min(max(d, 0), N_NODES - 1);
                int pos = atomicAdd(&deg[d], 1);
                if (pos < ELL_CAP) {
                    unsigned int val = (unsigned int)(ushort)s << (16 * (pos & 1));
                    atomicOr(&ell32[d * (ELL_CAP / 2) + (pos >> 1)], val);
                }
            }
        }
    } else {
        int gid = (blockIdx.x - EB) * 256 + threadIdx.x;
        int node = gid >> 6;
        int lane = gid & 63;
        if (node >= N_NODES) return;
        float m = (lane < D_IN) ? x[node * D_IN + lane] : 0.0f;
        float t = exp_proj_log(m);
        if (lane < D_IN) u0[node * D_IN + lane] = __float2half(t);
    }
}

// Repack W (f32 [K,64]) into B-fragment order for mfma_f32_16x16x32_f16:
// Whf[((jb*NF + f)*64 + lane)*8 + j] = W[f*32 + (lane>>4)*8 + j][jb*16 + (lane&15)]
template <int K>
__global__ void repack_kernel(const float* __restrict__ W, __half* __restrict__ Whf) {
    const int NF = K / 32;
    int idx = blockIdx.x * 256 + threadIdx.x;
    if (idx >= 4 * NF * 64 * 8) return;
    int j = idx & 7;
    int lane = (idx >> 3) & 63;
    int f = (idx >> 9) % NF;
    int jb = (idx >> 9) / NF;
    int k = f * 32 + ((lane >> 4) * 8) + j;
    int n = jb * 16 + (lane & 15);
    Whf[idx] = __float2half(W[k * 64 + n]);
}

// t[N,64] fp16 = u[N,K] fp16 @ W + b via MFMA. One wave = 16 nodes x 16 cols.
template <int K>
__global__ void gemm_kernel(const __half* __restrict__ u, const __half* __restrict__ Whf,
                            const float* __restrict__ b, __half* __restrict__ t) {
    const int NF = K / 32;
    int gw = blockIdx.x * 4 + (threadIdx.x >> 6);
    int lane = threadIdx.x & 63;
    int jb = gw & 3;
    int tile = gw >> 2;
    int node0 = tile * 16;
    if (node0 >= N_NODES) return;
    int m = lane & 15, quad = lane >> 4;

    float4v acc = {0.f, 0.f, 0.f, 0.f};
    const half8* bfr = (const half8*)Whf + (size_t)(jb * NF) * 64 + lane;
    #pragma unroll
    for (int f = 0; f < NF; ++f) {
        half8 a = *(const half8*)(u + (size_t)(node0 + m) * K + f * 32 + quad * 8);
        half8 bb = bfr[f * 64];
        acc = __builtin_amdgcn_mfma_f32_16x16x32_f16(a, bb, acc, 0, 0, 0);
    }
    int j = jb * 16 + m;
    float bias = b[j];
    #pragma unroll
    for (int r = 0; r < 4; ++r) {
        int node = node0 + quad * 4 + r;   // C/D: col=lane&15, row=quad*4+reg
        t[node * 64 + j] = __float2half(acc[r] + bias);
    }
}

// Gather-mean over ELL: dual-edge half2 pattern (half-wave per edge, lane
// owns dims 2*d2, 2*d2+1; uniform readlanes precomputed, THEN v_cndmask
// half-select) with EIGHT loads in flight (16 edges/iter). Then act ->
// expmap0 -> proj -> logmap0 -> fp16 store, or (POOL) block LDS combine +
// 1 atomic burst per block.
template <int ACT, int POOL>
__global__ void agg_kernel(const __half* __restrict__ t, const int* __restrict__ deg,
                           const ushort* __restrict__ ell, __half* __restrict__ uout,
                           const int* __restrict__ batch, float* __restrict__ pooled,
                           float* __restrict__ cntg) {
    __shared__ float rs[4][64];
    __shared__ int gs[4];
    int widx = threadIdx.x >> 6;
    int lane = threadIdx.x & 63;
    int node = blockIdx.x * 4 + widx;
    if (node >= N_NODES) return;   // never taken when POOL (50000 % 4 == 0)
    bool lo = lane < 32;
    int d2 = lane & 31;
    int dt = deg[node];
    int d = min(dt, ELL_CAP);
    // one coalesced 128B load: lane e holds neighbor id e
    int id = (lane < d) ? (int)ell[node * ELL_CAP + lane] : 0;
    const __half2* t2 = (const __half2*)t;

    float ax = 0.f, ay = 0.f;
    int e = 0;
    for (; e + 16 <= d; e += 16) {   // 16 edges, 8 wave-loads in flight
        int sA0 = __shfl(id, e,      64), sB0 = __shfl(id, e + 1,  64);
        int sA1 = __shfl(id, e + 2,  64), sB1 = __shfl(id, e + 3,  64);
        int sA2 = __shfl(id, e + 4,  64), sB2 = __shfl(id, e + 5,  64);
        int sA3 = __shfl(id, e + 6,  64), sB3 = __shfl(id, e + 7,  64);
        int sA4 = __shfl(id, e + 8,  64), sB4 = __shfl(id, e + 9,  64);
        int sA5 = __shfl(id, e + 10, 64), sB5 = __shfl(id, e + 11, 64);
        int sA6 = __shfl(id, e + 12, 64), sB6 = __shfl(id, e + 13, 64);
        int sA7 = __shfl(id, e + 14, 64), sB7 = __shfl(id, e + 15, 64);
        int s0 = lo ? sA0 : sB0;
        int s1 = lo ? sA1 : sB1;
        int s2 = lo ? sA2 : sB2;
        int s3 = lo ? sA3 : sB3;
        int s4 = lo ? sA4 : sB4;
        int s5 = lo ? sA5 : sB5;
        int s6 = lo ? sA6 : sB6;
        int s7 = lo ? sA7 : sB7;
        float2 f0 = __half22float2(t2[s0 * 32 + d2]);
        float2 f1 = __half22float2(t2[s1 * 32 + d2]);
        float2 f2 = __half22float2(t2[s2 * 32 + d2]);
        float2 f3 = __half22float2(t2[s3 * 32 + d2]);
        float2 f4 = __half22float2(t2[s4 * 32 + d2]);
        float2 f5 = __half22float2(t2[s5 * 32 + d2]);
        float2 f6 = __half22float2(t2[s6 * 32 + d2]);
        float2 f7 = __half22float2(t2[s7 * 32 + d2]);
        ax += ((f0.x + f1.x) + (f2.x + f3.x)) + ((f4.x + f5.x) + (f6.x + f7.x));
        ay += ((f0.y + f1.y) + (f2.y + f3.y)) + ((f4.y + f5.y) + (f6.y + f7.y));
    }
    if (e + 8 <= d) {                // 8 edges, 4 loads
        int sA0 = __shfl(id, e,     64), sB0 = __shfl(id, e + 1, 64);
        int sA1 = __shfl(id, e + 2, 64), sB1 = __shfl(id, e + 3, 64);
        int sA2 = __shfl(id, e + 4, 64), sB2 = __shfl(id, e + 5, 64);
        int sA3 = __shfl(id, e + 6, 64), sB3 = __shfl(id, e + 7, 64);
        int s0 = lo ? sA0 : sB0;
        int s1 = lo ? sA1 : sB1;
        int s2 = lo ? sA2 : sB2;
        int s3 = lo ? sA3 : sB3;
        float2 f0 = __half22float2(t2[s0 * 32 + d2]);
        float2 f1 = __half22float2(t2[s1 * 32 + d2]);
        float2 f2 = __half22float2(t2[s2 * 32 + d2]);
        float2 f3 = __half22float2(t2[s3 * 32 + d2]);
        ax += (f0.x + f1.x) + (f2.x + f3.x);
        ay += (f0.y + f1.y) + (f2.y + f3.y);
        e += 8;
    }
    for (; e + 2 <= d; e += 2) {
        int sA = __shfl(id, e, 64), sB = __shfl(id, e + 1, 64);
        int s = lo ? sA : sB;
        float2 f = __half22float2(t2[s * 32 + d2]);
        ax += f.x; ay += f.y;
    }
    if (e < d) {                     // odd leftover: half 0 only
        int s = __shfl(id, e, 64);
        if (lo) {
            float2 f = __half22float2(t2[s * 32 + d2]);
            ax += f.x; ay += f.y;
        }
    }
    ax += __shfl_xor(ax, 32, 64);    // combine halves; both hold full sums
    ay += __shfl_xor(ay, 32, 64);

    float inv = 1.0f / fmaxf((float)dt, 1.0f);
    float mx = ax * inv, my = ay * inv;
    if (ACT) {
        mx = (mx >= 0.f) ? mx : 0.2f * mx;
        my = (my >= 0.f) ? my : 0.2f * my;
    }
    // expmap0 -> proj -> logmap0 on the dim pair (32-lane reductions)
    float n = fmaxf(sqrtf(reduce32(mx * mx + my * my)), EPS);
    float s = tanhf(n) / n;
    float vx = s * mx, vy = s * my;
    float nv = fmaxf(sqrtf(reduce32(vx * vx + vy * vy)), EPS);
    if (nv > MAX_NORM) { float sc = MAX_NORM / nv; vx *= sc; vy *= sc; }
    float nl = sqrtf(reduce32(vx * vx + vy * vy));
    nl = fminf(fmaxf(nl, EPS), MAX_NORM);
    float sl = atanhf(nl) / nl;
    float rx = sl * vx, ry = sl * vy;

    if (POOL) {
        int g = min(max(batch[node], 0), N_GRAPHS - 1);
        if (lo) { rs[widx][2 * d2] = rx; rs[widx][2 * d2 + 1] = ry; }
        if (lane == 0) gs[widx] = g;
        __syncthreads();
        int g0 = gs[0], g1 = gs[1], g2 = gs[2], g3 = gs[3];
        bool uni = (g0 == g1) && (g1 == g2) && (g2 == g3);
        if (uni) {
            // sorted batch -> ~99% of blocks: one 64-lane burst per block
            if (widx == 0) {
                float sum = rs[0][lane] + rs[1][lane] + rs[2][lane] + rs[3][lane];
                atomicAdd(&pooled[g0 * 64 + lane], sum);
                if (lane == 0) atomicAdd(&cntg[g0], 4.0f);
            }
        } else {
            if (lo) {
                atomicAdd(&pooled[g * 64 + 2 * d2], rx);
                atomicAdd(&pooled[g * 64 + 2 * d2 + 1], ry);
            }
            if (lane == 0) atomicAdd(&cntg[g], 1.0f);
        }
    } else {
        if (lo) ((__half2*)uout)[node * 32 + d2] = __floats2half2_rn(rx, ry);
    }
}

// final head: mean -> exp/proj/log -> @Wl + bl -> expmap0 -> proj
__global__ void head_kernel(const float* __restrict__ pooled, const float* __restrict__ cntg,
                            const float* __restrict__ Wl, const float* __restrict__ bl,
                            float* __restrict__ out) {
    int g = blockIdx.x;
    int lane = threadIdx.x;
    float m = pooled[g * 64 + lane] / fmaxf(cntg[g], 1.0f);
    float z = exp_proj_log(m);
    float acc = 0.0f;
    #pragma unroll
    for (int k = 0; k < 64; ++k) {
        float zk = __shfl(z, k, 64);
        if (lane < D_OUT) acc = fmaf(zk, Wl[k * D_OUT + lane], acc);
    }
    float o = (lane < D_OUT) ? (acc + bl[lane]) : 0.0f;
    float n = fmaxf(sqrtf(wave_reduce_sum(o * o)), EPS);
    float v = tanhf(n) * o / n;
    float nv = fmaxf(sqrtf(wave_reduce_sum(v * v)), EPS);
    if (nv > MAX_NORM) v = v * (MAX_NORM / nv);
    if (lane < D_OUT) out[g * D_OUT + lane] = v;
}

// ---------------- launch ----------------

extern "C" void kernel_launch(void* const* d_in, const int* in_sizes, int n_in,
                              void* d_out, int out_size, void* d_ws, size_t ws_size,
                              hipStream_t stream) {
    const float* x   = (const float*)d_in[0];
    const int* edge  = (const int*)d_in[1];   // [2, E]
    const int* batch = (const int*)d_in[2];
    const float* W1  = (const float*)d_in[3];
    const float* b1  = (const float*)d_in[4];
    const float* W2  = (const float*)d_in[5];
    const float* b2  = (const float*)d_in[6];
    const float* W3  = (const float*)d_in[7];
    const float* b3  = (const float*)d_in[8];
    const float* Wl  = (const float*)d_in[9];
    const float* bl  = (const float*)d_in[10];
    float* out = (float*)d_out;

    const int N = N_NODES, E = N_EDGES, G = N_GRAPHS;
    const int* src = edge;
    const int* dst = edge + E;

    // ws layout: [deg:int N][pooled:f G*64][cntg:f G][ell:u16 N*64]
    //            [u0h:h N*32][u1h:h N*64][u2h:h N*64][th:h N*64][Wh1][Wh2][Wh3]
    char* ws = (char*)d_ws;
    int*    deg    = (int*)ws;
    float*  pooled = (float*)(deg + N);
    float*  cntg   = pooled + (size_t)G * 64;
    ushort* ell    = (ushort*)(cntg + G);
    __half* u0h    = (__half*)(ell + (size_t)N * ELL_CAP);
    __half* u1h    = u0h + (size_t)N * 32;
    __half* u2h    = u1h + (size_t)N * 64;
    __half* th     = u2h + (size_t)N * 64;
    __half* Wh1    = th + (size_t)N * 64;     // 2048
    __half* Wh2    = Wh1 + 2048;              // 4096
    __half* Wh3    = Wh2 + 4096;              // 4096

    // zero deg/pooled/cntg AND the ELL table (atomicOr needs zeroed words;
    // all four regions are contiguous at the head of ws)
    size_t zero_bytes = ((size_t)N + (size_t)G * 64 + G) * 4 + (size_t)N * ELL_CAP * 2;
    hipMemsetAsync(d_ws, 0, zero_bytes, stream);

    int blocksN64 = (N * 64 + 255) / 256;   // one wave per node, 4 per block
    int blocksB   = EB + blocksN64;         // fused build: edges first, then tangent0
    int blocksG   = 3125;                   // 50000/16 tiles * 4 col-waves / 4 per block

    repack_kernel<32><<<8,  256, 0, stream>>>(W1, Wh1);
    repack_kernel<64><<<16, 256, 0, stream>>>(W2, Wh2);
    repack_kernel<64><<<16, 256, 0, stream>>>(W3, Wh3);
    build_kernel<<<blocksB, 256, 0, stream>>>(src, dst, deg, (unsigned int*)ell, x, u0h);

    // layer 1: t = u0@W1+b1 (MFMA, fp16 out); gather-mean -> lrelu -> epl -> u1h
    gemm_kernel<32><<<blocksG, 256, 0, stream>>>(u0h, Wh1, b1, th);
    agg_kernel<1, 0><<<blocksN64, 256, 0, stream>>>(th, deg, ell, u1h, nullptr, nullptr, nullptr);
    // layer 2
    gemm_kernel<64><<<blocksG, 256, 0, stream>>>(u1h, Wh2, b2, th);
    agg_kernel<1, 0><<<blocksN64, 256, 0, stream>>>(th, deg, ell, u2h, nullptr, nullptr, nullptr);
    // layer 3 (no act) + LDS-combined pooling
    gemm_kernel<64><<<blocksG, 256, 0, stream>>>(u2h, Wh3, b3, th);
    agg_kernel<0, 1><<<blocksN64, 256, 0, stream>>>(th, deg, ell, nullptr, batch, pooled, cntg);

    head_kernel<<<G, 64, 0, stream>>>(pooled, cntg, Wl, bl, out);
}

// Round 13
// 397.026 us; speedup vs baseline: 1.0343x; 1.0343x over previous
//
#include <hip/hip_runtime.h>
#include <hip/hip_fp16.h>
#include <math.h>

#define N_NODES 50000
#define N_EDGES 1200000
#define N_GRAPHS 128
#define D_IN 32
#define D_H 64
#define D_OUT 10
#define ELL_CAP 64

#define EPS 1e-7f
#define MAX_NORM (1.0f - 1e-5f)

typedef _Float16 half8 __attribute__((ext_vector_type(8)));
typedef float float4v __attribute__((ext_vector_type(4)));

// ---------------- wave helpers ----------------

__device__ __forceinline__ float wave_reduce_sum(float v) {
    #pragma unroll
    for (int off = 32; off > 0; off >>= 1)
        v += __shfl_xor(v, off, 64);
    return v;
}

// sum over the 32 lanes of each half (halves hold identical data -> both
// halves end with the full sum)
__device__ __forceinline__ float reduce32(float v) {
    #pragma unroll
    for (int off = 16; off > 0; off >>= 1)
        v += __shfl_xor(v, off, 64);
    return v;
}

// logmap0(proj(expmap0(u))) on a 64-lane-distributed vector.
__device__ __forceinline__ float exp_proj_log(float m) {
    float n = fmaxf(sqrtf(wave_reduce_sum(m * m)), EPS);
    float v = tanhf(n) * m / n;
    float nv = fmaxf(sqrtf(wave_reduce_sum(v * v)), EPS);
    if (nv > MAX_NORM) v = v * (MAX_NORM / nv);
    float nl = sqrtf(wave_reduce_sum(v * v));
    nl = fminf(fmaxf(nl, EPS), MAX_NORM);
    return atanhf(nl) * v / nl;
}

// ---------------- kernels ----------------

// Fused build: [blocks 0..EB) ELL build, ONE edge per thread (max TLP — the
// R2-measured fastest config for this op: scattered store/atomic cost is a
// per-op fabric transaction; more waves = more in flight. ILP variants (R9)
// and atomicOr packing (R12) were both slower or neutral). [EB..): tangent0.
#define EB ((N_EDGES + 255) / 256)
__global__ void build_kernel(const int* __restrict__ src, const int* __restrict__ dst,
                             int* __restrict__ deg, ushort* __restrict__ ell,
                             const float* __restrict__ x, __half* __restrict__ u0) {
    if (blockIdx.x < EB) {
        int e = blockIdx.x * 256 + threadIdx.x;
        if (e < N_EDGES) {
            int s = src[e];
            int d = dst[e];
            s = min(max(s, 0), N_NODES - 1);
            d = min(max(d, 0), N_NODES - 1);
            int pos = atomicAdd(&deg[d], 1);
            if (pos < ELL_CAP) ell[d * ELL_CAP + pos] = (ushort)s;
        }
    } else {
        int gid = (blockIdx.x - EB) * 256 + threadIdx.x;
        int node = gid >> 6;
        int lane = gid & 63;
        if (node >= N_NODES) return;
        float m = (lane < D_IN) ? x[node * D_IN + lane] : 0.0f;
        float t = exp_proj_log(m);
        if (lane < D_IN) u0[node * D_IN + lane] = __float2half(t);
    }
}

// Repack W (f32 [K,64]) into B-fragment order for mfma_f32_16x16x32_f16:
// Whf[((jb*NF + f)*64 + lane)*8 + j] = W[f*32 + (lane>>4)*8 + j][jb*16 + (lane&15)]
template <int K>
__global__ void repack_kernel(const float* __restrict__ W, __half* __restrict__ Whf) {
    const int NF = K / 32;
    int idx = blockIdx.x * 256 + threadIdx.x;
    if (idx >= 4 * NF * 64 * 8) return;
    int j = idx & 7;
    int lane = (idx >> 3) & 63;
    int f = (idx >> 9) % NF;
    int jb = (idx >> 9) / NF;
    int k = f * 32 + ((lane >> 4) * 8) + j;
    int n = jb * 16 + (lane & 15);
    Whf[idx] = __float2half(W[k * 64 + n]);
}

// t[N,64] fp16 = u[N,K] fp16 @ W + b via MFMA. One wave = 16 nodes x 16 cols.
template <int K>
__global__ void gemm_kernel(const __half* __restrict__ u, const __half* __restrict__ Whf,
                            const float* __restrict__ b, __half* __restrict__ t) {
    const int NF = K / 32;
    int gw = blockIdx.x * 4 + (threadIdx.x >> 6);
    int lane = threadIdx.x & 63;
    int jb = gw & 3;
    int tile = gw >> 2;
    int node0 = tile * 16;
    if (node0 >= N_NODES) return;
    int m = lane & 15, quad = lane >> 4;

    float4v acc = {0.f, 0.f, 0.f, 0.f};
    const half8* bfr = (const half8*)Whf + (size_t)(jb * NF) * 64 + lane;
    #pragma unroll
    for (int f = 0; f < NF; ++f) {
        half8 a = *(const half8*)(u + (size_t)(node0 + m) * K + f * 32 + quad * 8);
        half8 bb = bfr[f * 64];
        acc = __builtin_amdgcn_mfma_f32_16x16x32_f16(a, bb, acc, 0, 0, 0);
    }
    int j = jb * 16 + m;
    float bias = b[j];
    #pragma unroll
    for (int r = 0; r < 4; ++r) {
        int node = node0 + quad * 4 + r;   // C/D: col=lane&15, row=quad*4+reg
        t[node * 64 + j] = __float2half(acc[r] + bias);
    }
}

// Gather-mean over ELL: dual-edge half2 pattern (half-wave per edge, lane
// owns dims 2*d2, 2*d2+1; uniform readlanes precomputed, THEN v_cndmask
// half-select) with EIGHT loads in flight (16 edges/iter). Then act ->
// expmap0 -> proj -> logmap0 -> fp16 store, or (POOL) block LDS combine +
// 1 atomic burst per block.
template <int ACT, int POOL>
__global__ void agg_kernel(const __half* __restrict__ t, const int* __restrict__ deg,
                           const ushort* __restrict__ ell, __half* __restrict__ uout,
                           const int* __restrict__ batch, float* __restrict__ pooled,
                           float* __restrict__ cntg) {
    __shared__ float rs[4][64];
    __shared__ int gs[4];
    int widx = threadIdx.x >> 6;
    int lane = threadIdx.x & 63;
    int node = blockIdx.x * 4 + widx;
    if (node >= N_NODES) return;   // never taken when POOL (50000 % 4 == 0)
    bool lo = lane < 32;
    int d2 = lane & 31;
    int dt = deg[node];
    int d = min(dt, ELL_CAP);
    // one coalesced 128B load: lane e holds neighbor id e
    int id = (lane < d) ? (int)ell[node * ELL_CAP + lane] : 0;
    const __half2* t2 = (const __half2*)t;

    float ax = 0.f, ay = 0.f;
    int e = 0;
    for (; e + 16 <= d; e += 16) {   // 16 edges, 8 wave-loads in flight
        int sA0 = __shfl(id, e,      64), sB0 = __shfl(id, e + 1,  64);
        int sA1 = __shfl(id, e + 2,  64), sB1 = __shfl(id, e + 3,  64);
        int sA2 = __shfl(id, e + 4,  64), sB2 = __shfl(id, e + 5,  64);
        int sA3 = __shfl(id, e + 6,  64), sB3 = __shfl(id, e + 7,  64);
        int sA4 = __shfl(id, e + 8,  64), sB4 = __shfl(id, e + 9,  64);
        int sA5 = __shfl(id, e + 10, 64), sB5 = __shfl(id, e + 11, 64);
        int sA6 = __shfl(id, e + 12, 64), sB6 = __shfl(id, e + 13, 64);
        int sA7 = __shfl(id, e + 14, 64), sB7 = __shfl(id, e + 15, 64);
        int s0 = lo ? sA0 : sB0;
        int s1 = lo ? sA1 : sB1;
        int s2 = lo ? sA2 : sB2;
        int s3 = lo ? sA3 : sB3;
        int s4 = lo ? sA4 : sB4;
        int s5 = lo ? sA5 : sB5;
        int s6 = lo ? sA6 : sB6;
        int s7 = lo ? sA7 : sB7;
        float2 f0 = __half22float2(t2[s0 * 32 + d2]);
        float2 f1 = __half22float2(t2[s1 * 32 + d2]);
        float2 f2 = __half22float2(t2[s2 * 32 + d2]);
        float2 f3 = __half22float2(t2[s3 * 32 + d2]);
        float2 f4 = __half22float2(t2[s4 * 32 + d2]);
        float2 f5 = __half22float2(t2[s5 * 32 + d2]);
        float2 f6 = __half22float2(t2[s6 * 32 + d2]);
        float2 f7 = __half22float2(t2[s7 * 32 + d2]);
        ax += ((f0.x + f1.x) + (f2.x + f3.x)) + ((f4.x + f5.x) + (f6.x + f7.x));
        ay += ((f0.y + f1.y) + (f2.y + f3.y)) + ((f4.y + f5.y) + (f6.y + f7.y));
    }
    if (e + 8 <= d) {                // 8 edges, 4 loads
        int sA0 = __shfl(id, e,     64), sB0 = __shfl(id, e + 1, 64);
        int sA1 = __shfl(id, e + 2, 64), sB1 = __shfl(id, e + 3, 64);
        int sA2 = __shfl(id, e + 4, 64), sB2 = __shfl(id, e + 5, 64);
        int sA3 = __shfl(id, e + 6, 64), sB3 = __shfl(id, e + 7, 64);
        int s0 = lo ? sA0 : sB0;
        int s1 = lo ? sA1 : sB1;
        int s2 = lo ? sA2 : sB2;
        int s3 = lo ? sA3 : sB3;
        float2 f0 = __half22float2(t2[s0 * 32 + d2]);
        float2 f1 = __half22float2(t2[s1 * 32 + d2]);
        float2 f2 = __half22float2(t2[s2 * 32 + d2]);
        float2 f3 = __half22float2(t2[s3 * 32 + d2]);
        ax += (f0.x + f1.x) + (f2.x + f3.x);
        ay += (f0.y + f1.y) + (f2.y + f3.y);
        e += 8;
    }
    for (; e + 2 <= d; e += 2) {
        int sA = __shfl(id, e, 64), sB = __shfl(id, e + 1, 64);
        int s = lo ? sA : sB;
        float2 f = __half22float2(t2[s * 32 + d2]);
        ax += f.x; ay += f.y;
    }
    if (e < d) {                     // odd leftover: half 0 only
        int s = __shfl(id, e, 64);
        if (lo) {
            float2 f = __half22float2(t2[s * 32 + d2]);
            ax += f.x; ay += f.y;
        }
    }
    ax += __shfl_xor(ax, 32, 64);    // combine halves; both hold full sums
    ay += __shfl_xor(ay, 32, 64);

    float inv = 1.0f / fmaxf((float)dt, 1.0f);
    float mx = ax * inv, my = ay * inv;
    if (ACT) {
        mx = (mx >= 0.f) ? mx : 0.2f * mx;
        my = (my >= 0.f) ? my : 0.2f * my;
    }
    // expmap0 -> proj -> logmap0 on the dim pair (32-lane reductions)
    float n = fmaxf(sqrtf(reduce32(mx * mx + my * my)), EPS);
    float s = tanhf(n) / n;
    float vx = s * mx, vy = s * my;
    float nv = fmaxf(sqrtf(reduce32(vx * vx + vy * vy)), EPS);
    if (nv > MAX_NORM) { float sc = MAX_NORM / nv; vx *= sc; vy *= sc; }
    float nl = sqrtf(reduce32(vx * vx + vy * vy));
    nl = fminf(fmaxf(nl, EPS), MAX_NORM);
    float sl = atanhf(nl) / nl;
    float rx = sl * vx, ry = sl * vy;

    if (POOL) {
        int g = min(max(batch[node], 0), N_GRAPHS - 1);
        if (lo) { rs[widx][2 * d2] = rx; rs[widx][2 * d2 + 1] = ry; }
        if (lane == 0) gs[widx] = g;
        __syncthreads();
        int g0 = gs[0], g1 = gs[1], g2 = gs[2], g3 = gs[3];
        bool uni = (g0 == g1) && (g1 == g2) && (g2 == g3);
        if (uni) {
            // sorted batch -> ~99% of blocks: one 64-lane burst per block
            if (widx == 0) {
                float sum = rs[0][lane] + rs[1][lane] + rs[2][lane] + rs[3][lane];
                atomicAdd(&pooled[g0 * 64 + lane], sum);
                if (lane == 0) atomicAdd(&cntg[g0], 4.0f);
            }
        } else {
            if (lo) {
                atomicAdd(&pooled[g * 64 + 2 * d2], rx);
                atomicAdd(&pooled[g * 64 + 2 * d2 + 1], ry);
            }
            if (lane == 0) atomicAdd(&cntg[g], 1.0f);
        }
    } else {
        if (lo) ((__half2*)uout)[node * 32 + d2] = __floats2half2_rn(rx, ry);
    }
}

// final head: mean -> exp/proj/log -> @Wl + bl -> expmap0 -> proj
__global__ void head_kernel(const float* __restrict__ pooled, const float* __restrict__ cntg,
                            const float* __restrict__ Wl, const float* __restrict__ bl,
                            float* __restrict__ out) {
    int g = blockIdx.x;
    int lane = threadIdx.x;
    float m = pooled[g * 64 + lane] / fmaxf(cntg[g], 1.0f);
    float z = exp_proj_log(m);
    float acc = 0.0f;
    #pragma unroll
    for (int k = 0; k < 64; ++k) {
        float zk = __shfl(z, k, 64);
        if (lane < D_OUT) acc = fmaf(zk, Wl[k * D_OUT + lane], acc);
    }
    float o = (lane < D_OUT) ? (acc + bl[lane]) : 0.0f;
    float n = fmaxf(sqrtf(wave_reduce_sum(o * o)), EPS);
    float v = tanhf(n) * o / n;
    float nv = fmaxf(sqrtf(wave_reduce_sum(v * v)), EPS);
    if (nv > MAX_NORM) v = v * (MAX_NORM / nv);
    if (lane < D_OUT) out[g * D_OUT + lane] = v;
}

// ---------------- launch ----------------

extern "C" void kernel_launch(void* const* d_in, const int* in_sizes, int n_in,
                              void* d_out, int out_size, void* d_ws, size_t ws_size,
                              hipStream_t stream) {
    const float* x   = (const float*)d_in[0];
    const int* edge  = (const int*)d_in[1];   // [2, E]
    const int* batch = (const int*)d_in[2];
    const float* W1  = (const float*)d_in[3];
    const float* b1  = (const float*)d_in[4];
    const float* W2  = (const float*)d_in[5];
    const float* b2  = (const float*)d_in[6];
    const float* W3  = (const float*)d_in[7];
    const float* b3  = (const float*)d_in[8];
    const float* Wl  = (const float*)d_in[9];
    const float* bl  = (const float*)d_in[10];
    float* out = (float*)d_out;

    const int N = N_NODES, E = N_EDGES, G = N_GRAPHS;
    const int* src = edge;
    const int* dst = edge + E;

    // ws layout: [deg:int N][pooled:f G*64][cntg:f G][ell:u16 N*64]
    //            [u0h:h N*32][u1h:h N*64][u2h:h N*64][th:h N*64][Wh1][Wh2][Wh3]
    char* ws = (char*)d_ws;
    int*    deg    = (int*)ws;
    float*  pooled = (float*)(deg + N);
    float*  cntg   = pooled + (size_t)G * 64;
    ushort* ell    = (ushort*)(cntg + G);
    __half* u0h    = (__half*)(ell + (size_t)N * ELL_CAP);
    __half* u1h    = u0h + (size_t)N * 32;
    __half* u2h    = u1h + (size_t)N * 64;
    __half* th     = u2h + (size_t)N * 64;
    __half* Wh1    = th + (size_t)N * 64;     // 2048
    __half* Wh2    = Wh1 + 2048;              // 4096
    __half* Wh3    = Wh2 + 4096;              // 4096

    // zero deg/pooled/cntg only (plain-store ELL needs no pre-zero)
    size_t zero_bytes = ((size_t)N + (size_t)G * 64 + G) * 4;
    hipMemsetAsync(d_ws, 0, zero_bytes, stream);

    int blocksN64 = (N * 64 + 255) / 256;   // one wave per node, 4 per block
    int blocksB   = EB + blocksN64;         // build (1 thread/edge) + tangent0 tail
    int blocksG   = 3125;                   // 50000/16 tiles * 4 col-waves / 4 per block

    repack_kernel<32><<<8,  256, 0, stream>>>(W1, Wh1);
    repack_kernel<64><<<16, 256, 0, stream>>>(W2, Wh2);
    repack_kernel<64><<<16, 256, 0, stream>>>(W3, Wh3);
    build_kernel<<<blocksB, 256, 0, stream>>>(src, dst, deg, ell, x, u0h);

    // layer 1: t = u0@W1+b1 (MFMA, fp16 out); gather-mean -> lrelu -> epl -> u1h
    gemm_kernel<32><<<blocksG, 256, 0, stream>>>(u0h, Wh1, b1, th);
    agg_kernel<1, 0><<<blocksN64, 256, 0, stream>>>(th, deg, ell, u1h, nullptr, nullptr, nullptr);
    // layer 2
    gemm_kernel<64><<<blocksG, 256, 0, stream>>>(u1h, Wh2, b2, th);
    agg_kernel<1, 0><<<blocksN64, 256, 0, stream>>>(th, deg, ell, u2h, nullptr, nullptr, nullptr);
    // layer 3 (no act) + LDS-combined pooling
    gemm_kernel<64><<<blocksG, 256, 0, stream>>>(u2h, Wh3, b3, th);
    agg_kernel<0, 1><<<blocksN64, 256, 0, stream>>>(th, deg, ell, nullptr, batch, pooled, cntg);

    head_kernel<<<G, 64, 0, stream>>>(pooled, cntg, Wl, bl, out);
}

// Round 14
// 363.513 us; speedup vs baseline: 1.1297x; 1.0922x over previous
//
#include <hip/hip_runtime.h>
#include <hip/hip_fp16.h>
#include <math.h>

#define N_NODES 50000
#define N_EDGES 1200000
#define N_GRAPHS 128
#define D_IN 32
#define D_H 64
#define D_OUT 10
#define ELL_CAP 64

#define EPS 1e-7f
#define MAX_NORM (1.0f - 1e-5f)
// atanh(MAX_NORM): logmap0(proj(expmap0(m))) == m * min(1, TCLIP/||m||)
// (exact in real arithmetic; see R14 notes — tanh/atanh cancel, proj clips
// the norm at MAX_NORM which pulls the tangent norm back to atanh(MAX_NORM))
#define TCLIP 6.1030335f

typedef _Float16 half8 __attribute__((ext_vector_type(8)));
typedef float float4v __attribute__((ext_vector_type(4)));

// ---------------- wave helpers ----------------

__device__ __forceinline__ float wave_reduce_sum(float v) {
    #pragma unroll
    for (int off = 32; off > 0; off >>= 1)
        v += __shfl_xor(v, off, 64);
    return v;
}

// sum over the 32 lanes of each half (halves hold identical data -> both
// halves end with the full sum)
__device__ __forceinline__ float reduce32(float v) {
    #pragma unroll
    for (int off = 16; off > 0; off >>= 1)
        v += __shfl_xor(v, off, 64);
    return v;
}

// logmap0(proj(expmap0(m))) collapsed to a norm clip (one reduction).
__device__ __forceinline__ float epl_clip64(float m) {
    float n = sqrtf(wave_reduce_sum(m * m));
    float sc = (n > TCLIP) ? (TCLIP / n) : 1.0f;
    return m * sc;
}

// ---------------- kernels ----------------

// Fused build: [blocks 0..EB) ELL build, one edge per thread; [EB..):
// tangent0 = fp16(clip(x)) (epilogue collapse — R14).
#define EB ((N_EDGES + 255) / 256)
__global__ void build_kernel(const int* __restrict__ src, const int* __restrict__ dst,
                             int* __restrict__ deg, ushort* __restrict__ ell,
                             const float* __restrict__ x, __half* __restrict__ u0) {
    if (blockIdx.x < EB) {
        int e = blockIdx.x * 256 + threadIdx.x;
        if (e < N_EDGES) {
            int s = src[e];
            int d = dst[e];
            s = min(max(s, 0), N_NODES - 1);
            d = min(max(d, 0), N_NODES - 1);
            int pos = atomicAdd(&deg[d], 1);
            if (pos < ELL_CAP) ell[d * ELL_CAP + pos] = (ushort)s;
        }
    } else {
        int gid = (blockIdx.x - EB) * 256 + threadIdx.x;
        int node = gid >> 6;
        int lane = gid & 63;
        if (node >= N_NODES) return;
        float m = (lane < D_IN) ? x[node * D_IN + lane] : 0.0f;
        float t = epl_clip64(m);
        if (lane < D_IN) u0[node * D_IN + lane] = __float2half(t);
    }
}

// Repack W (f32 [K,64]) into B-fragment order for mfma_f32_16x16x32_f16:
// Whf[((jb*NF + f)*64 + lane)*8 + j] = W[f*32 + (lane>>4)*8 + j][jb*16 + (lane&15)]
template <int K>
__global__ void repack_kernel(const float* __restrict__ W, __half* __restrict__ Whf) {
    const int NF = K / 32;
    int idx = blockIdx.x * 256 + threadIdx.x;
    if (idx >= 4 * NF * 64 * 8) return;
    int j = idx & 7;
    int lane = (idx >> 3) & 63;
    int f = (idx >> 9) % NF;
    int jb = (idx >> 9) / NF;
    int k = f * 32 + ((lane >> 4) * 8) + j;
    int n = jb * 16 + (lane & 15);
    Whf[idx] = __float2half(W[k * 64 + n]);
}

// t[N,64] fp16 = u[N,K] fp16 @ W + b via MFMA. One wave = 16 nodes x 16 cols.
template <int K>
__global__ void gemm_kernel(const __half* __restrict__ u, const __half* __restrict__ Whf,
                            const float* __restrict__ b, __half* __restrict__ t) {
    const int NF = K / 32;
    int gw = blockIdx.x * 4 + (threadIdx.x >> 6);
    int lane = threadIdx.x & 63;
    int jb = gw & 3;
    int tile = gw >> 2;
    int node0 = tile * 16;
    if (node0 >= N_NODES) return;
    int m = lane & 15, quad = lane >> 4;

    float4v acc = {0.f, 0.f, 0.f, 0.f};
    const half8* bfr = (const half8*)Whf + (size_t)(jb * NF) * 64 + lane;
    #pragma unroll
    for (int f = 0; f < NF; ++f) {
        half8 a = *(const half8*)(u + (size_t)(node0 + m) * K + f * 32 + quad * 8);
        half8 bb = bfr[f * 64];
        acc = __builtin_amdgcn_mfma_f32_16x16x32_f16(a, bb, acc, 0, 0, 0);
    }
    int j = jb * 16 + m;
    float bias = b[j];
    #pragma unroll
    for (int r = 0; r < 4; ++r) {
        int node = node0 + quad * 4 + r;   // C/D: col=lane&15, row=quad*4+reg
        t[node * 64 + j] = __float2half(acc[r] + bias);
    }
}

// Gather-mean over ELL (dual-edge half2, 8 loads in flight) -> act ->
// NORM-CLIP epilogue (one 32-lane reduction — collapsed exp/proj/log) ->
// fp16 store, or (POOL) block LDS combine + 1 atomic burst per block.
template <int ACT, int POOL>
__global__ void agg_kernel(const __half* __restrict__ t, const int* __restrict__ deg,
                           const ushort* __restrict__ ell, __half* __restrict__ uout,
                           const int* __restrict__ batch, float* __restrict__ pooled,
                           float* __restrict__ cntg) {
    __shared__ float rs[4][64];
    __shared__ int gs[4];
    int widx = threadIdx.x >> 6;
    int lane = threadIdx.x & 63;
    int node = blockIdx.x * 4 + widx;
    if (node >= N_NODES) return;   // never taken when POOL (50000 % 4 == 0)
    bool lo = lane < 32;
    int d2 = lane & 31;
    int dt = deg[node];
    int d = min(dt, ELL_CAP);
    // one coalesced 128B load: lane e holds neighbor id e
    int id = (lane < d) ? (int)ell[node * ELL_CAP + lane] : 0;
    const __half2* t2 = (const __half2*)t;

    float ax = 0.f, ay = 0.f;
    int e = 0;
    for (; e + 16 <= d; e += 16) {   // 16 edges, 8 wave-loads in flight
        int sA0 = __shfl(id, e,      64), sB0 = __shfl(id, e + 1,  64);
        int sA1 = __shfl(id, e + 2,  64), sB1 = __shfl(id, e + 3,  64);
        int sA2 = __shfl(id, e + 4,  64), sB2 = __shfl(id, e + 5,  64);
        int sA3 = __shfl(id, e + 6,  64), sB3 = __shfl(id, e + 7,  64);
        int sA4 = __shfl(id, e + 8,  64), sB4 = __shfl(id, e + 9,  64);
        int sA5 = __shfl(id, e + 10, 64), sB5 = __shfl(id, e + 11, 64);
        int sA6 = __shfl(id, e + 12, 64), sB6 = __shfl(id, e + 13, 64);
        int sA7 = __shfl(id, e + 14, 64), sB7 = __shfl(id, e + 15, 64);
        int s0 = lo ? sA0 : sB0;
        int s1 = lo ? sA1 : sB1;
        int s2 = lo ? sA2 : sB2;
        int s3 = lo ? sA3 : sB3;
        int s4 = lo ? sA4 : sB4;
        int s5 = lo ? sA5 : sB5;
        int s6 = lo ? sA6 : sB6;
        int s7 = lo ? sA7 : sB7;
        float2 f0 = __half22float2(t2[s0 * 32 + d2]);
        float2 f1 = __half22float2(t2[s1 * 32 + d2]);
        float2 f2 = __half22float2(t2[s2 * 32 + d2]);
        float2 f3 = __half22float2(t2[s3 * 32 + d2]);
        float2 f4 = __half22float2(t2[s4 * 32 + d2]);
        float2 f5 = __half22float2(t2[s5 * 32 + d2]);
        float2 f6 = __half22float2(t2[s6 * 32 + d2]);
        float2 f7 = __half22float2(t2[s7 * 32 + d2]);
        ax += ((f0.x + f1.x) + (f2.x + f3.x)) + ((f4.x + f5.x) + (f6.x + f7.x));
        ay += ((f0.y + f1.y) + (f2.y + f3.y)) + ((f4.y + f5.y) + (f6.y + f7.y));
    }
    if (e + 8 <= d) {                // 8 edges, 4 loads
        int sA0 = __shfl(id, e,     64), sB0 = __shfl(id, e + 1, 64);
        int sA1 = __shfl(id, e + 2, 64), sB1 = __shfl(id, e + 3, 64);
        int sA2 = __shfl(id, e + 4, 64), sB2 = __shfl(id, e + 5, 64);
        int sA3 = __shfl(id, e + 6, 64), sB3 = __shfl(id, e + 7, 64);
        int s0 = lo ? sA0 : sB0;
        int s1 = lo ? sA1 : sB1;
        int s2 = lo ? sA2 : sB2;
        int s3 = lo ? sA3 : sB3;
        float2 f0 = __half22float2(t2[s0 * 32 + d2]);
        float2 f1 = __half22float2(t2[s1 * 32 + d2]);
        float2 f2 = __half22float2(t2[s2 * 32 + d2]);
        float2 f3 = __half22float2(t2[s3 * 32 + d2]);
        ax += (f0.x + f1.x) + (f2.x + f3.x);
        ay += (f0.y + f1.y) + (f2.y + f3.y);
        e += 8;
    }
    for (; e + 2 <= d; e += 2) {
        int sA = __shfl(id, e, 64), sB = __shfl(id, e + 1, 64);
        int s = lo ? sA : sB;
        float2 f = __half22float2(t2[s * 32 + d2]);
        ax += f.x; ay += f.y;
    }
    if (e < d) {                     // odd leftover: half 0 only
        int s = __shfl(id, e, 64);
        if (lo) {
            float2 f = __half22float2(t2[s * 32 + d2]);
            ax += f.x; ay += f.y;
        }
    }
    ax += __shfl_xor(ax, 32, 64);    // combine halves; both hold full sums
    ay += __shfl_xor(ay, 32, 64);

    float inv = 1.0f / fmaxf((float)dt, 1.0f);
    float mx = ax * inv, my = ay * inv;
    if (ACT) {
        mx = (mx >= 0.f) ? mx : 0.2f * mx;
        my = (my >= 0.f) ? my : 0.2f * my;
    }
    // collapsed epilogue: logmap0(proj(expmap0(m))) == norm clip at TCLIP
    float n = sqrtf(reduce32(mx * mx + my * my));
    float sc = (n > TCLIP) ? (TCLIP / n) : 1.0f;
    float rx = mx * sc, ry = my * sc;

    if (POOL) {
        int g = min(max(batch[node], 0), N_GRAPHS - 1);
        if (lo) { rs[widx][2 * d2] = rx; rs[widx][2 * d2 + 1] = ry; }
        if (lane == 0) gs[widx] = g;
        __syncthreads();
        int g0 = gs[0], g1 = gs[1], g2 = gs[2], g3 = gs[3];
        bool uni = (g0 == g1) && (g1 == g2) && (g2 == g3);
        if (uni) {
            // sorted batch -> ~99% of blocks: one 64-lane burst per block
            if (widx == 0) {
                float sum = rs[0][lane] + rs[1][lane] + rs[2][lane] + rs[3][lane];
                atomicAdd(&pooled[g0 * 64 + lane], sum);
                if (lane == 0) atomicAdd(&cntg[g0], 4.0f);
            }
        } else {
            if (lo) {
                atomicAdd(&pooled[g * 64 + 2 * d2], rx);
                atomicAdd(&pooled[g * 64 + 2 * d2 + 1], ry);
            }
            if (lane == 0) atomicAdd(&cntg[g], 1.0f);
        }
    } else {
        if (lo) ((__half2*)uout)[node * 32 + d2] = __floats2half2_rn(rx, ry);
    }
}

// final head: mean -> clip (collapsed epl) -> @Wl + bl -> expmap0 -> proj
// (the FINAL expmap0+proj is the real output transform — kept literal)
__global__ void head_kernel(const float* __restrict__ pooled, const float* __restrict__ cntg,
                            const float* __restrict__ Wl, const float* __restrict__ bl,
                            float* __restrict__ out) {
    int g = blockIdx.x;
    int lane = threadIdx.x;
    float m = pooled[g * 64 + lane] / fmaxf(cntg[g], 1.0f);
    float z = epl_clip64(m);
    float acc = 0.0f;
    #pragma unroll
    for (int k = 0; k < 64; ++k) {
        float zk = __shfl(z, k, 64);
        if (lane < D_OUT) acc = fmaf(zk, Wl[k * D_OUT + lane], acc);
    }
    float o = (lane < D_OUT) ? (acc + bl[lane]) : 0.0f;
    float n = fmaxf(sqrtf(wave_reduce_sum(o * o)), EPS);
    float v = tanhf(n) * o / n;
    float nv = fmaxf(sqrtf(wave_reduce_sum(v * v)), EPS);
    if (nv > MAX_NORM) v = v * (MAX_NORM / nv);
    if (lane < D_OUT) out[g * D_OUT + lane] = v;
}

// ---------------- launch ----------------

extern "C" void kernel_launch(void* const* d_in, const int* in_sizes, int n_in,
                              void* d_out, int out_size, void* d_ws, size_t ws_size,
                              hipStream_t stream) {
    const float* x   = (const float*)d_in[0];
    const int* edge  = (const int*)d_in[1];   // [2, E]
    const int* batch = (const int*)d_in[2];
    const float* W1  = (const float*)d_in[3];
    const float* b1  = (const float*)d_in[4];
    const float* W2  = (const float*)d_in[5];
    const float* b2  = (const float*)d_in[6];
    const float* W3  = (const float*)d_in[7];
    const float* b3  = (const float*)d_in[8];
    const float* Wl  = (const float*)d_in[9];
    const float* bl  = (const float*)d_in[10];
    float* out = (float*)d_out;

    const int N = N_NODES, E = N_EDGES, G = N_GRAPHS;
    const int* src = edge;
    const int* dst = edge + E;

    // ws layout: [deg:int N][pooled:f G*64][cntg:f G][ell:u16 N*64]
    //            [u0h:h N*32][u1h:h N*64][u2h:h N*64][th:h N*64][Wh1][Wh2][Wh3]
    char* ws = (char*)d_ws;
    int*    deg    = (int*)ws;
    float*  pooled = (float*)(deg + N);
    float*  cntg   = pooled + (size_t)G * 64;
    ushort* ell    = (ushort*)(cntg + G);
    __half* u0h    = (__half*)(ell + (size_t)N * ELL_CAP);
    __half* u1h    = u0h + (size_t)N * 32;
    __half* u2h    = u1h + (size_t)N * 64;
    __half* th     = u2h + (size_t)N * 64;
    __half* Wh1    = th + (size_t)N * 64;     // 2048
    __half* Wh2    = Wh1 + 2048;              // 4096
    __half* Wh3    = Wh2 + 4096;              // 4096

    // zero deg/pooled/cntg only (plain-store ELL needs no pre-zero)
    size_t zero_bytes = ((size_t)N + (size_t)G * 64 + G) * 4;
    hipMemsetAsync(d_ws, 0, zero_bytes, stream);

    int blocksN64 = (N * 64 + 255) / 256;   // one wave per node, 4 per block
    int blocksB   = EB + blocksN64;         // build (1 thread/edge) + tangent0 tail
    int blocksG   = 3125;                   // 50000/16 tiles * 4 col-waves / 4 per block

    repack_kernel<32><<<8,  256, 0, stream>>>(W1, Wh1);
    repack_kernel<64><<<16, 256, 0, stream>>>(W2, Wh2);
    repack_kernel<64><<<16, 256, 0, stream>>>(W3, Wh3);
    build_kernel<<<blocksB, 256, 0, stream>>>(src, dst, deg, ell, x, u0h);

    // layer 1: t = u0@W1+b1 (MFMA, fp16 out); gather-mean -> lrelu -> clip -> u1h
    gemm_kernel<32><<<blocksG, 256, 0, stream>>>(u0h, Wh1, b1, th);
    agg_kernel<1, 0><<<blocksN64, 256, 0, stream>>>(th, deg, ell, u1h, nullptr, nullptr, nullptr);
    // layer 2
    gemm_kernel<64><<<blocksG, 256, 0, stream>>>(u1h, Wh2, b2, th);
    agg_kernel<1, 0><<<blocksN64, 256, 0, stream>>>(th, deg, ell, u2h, nullptr, nullptr, nullptr);
    // layer 3 (no act) + LDS-combined pooling
    gemm_kernel<64><<<blocksG, 256, 0, stream>>>(u2h, Wh3, b3, th);
    agg_kernel<0, 1><<<blocksN64, 256, 0, stream>>>(th, deg, ell, nullptr, batch, pooled, cntg);

    head_kernel<<<G, 64, 0, stream>>>(pooled, cntg, Wl, bl, out);
}

// Round 15
// 347.302 us; speedup vs baseline: 1.1824x; 1.0467x over previous
//
#include <hip/hip_runtime.h>
#include <hip/hip_fp16.h>
#include <math.h>

#define N_NODES 50000
#define N_EDGES 1200000
#define N_GRAPHS 128
#define D_IN 32
#define D_H 64
#define D_OUT 10
#define ELL_CAP 64

#define EPS 1e-7f
#define MAX_NORM (1.0f - 1e-5f)
// atanh(MAX_NORM): logmap0(proj(expmap0(m))) == m * min(1, TCLIP/||m||)
#define TCLIP 6.1030335f

typedef _Float16 half8 __attribute__((ext_vector_type(8)));
typedef float float4v __attribute__((ext_vector_type(4)));

// ---------------- wave helpers ----------------

__device__ __forceinline__ float wave_reduce_sum(float v) {
    #pragma unroll
    for (int off = 32; off > 0; off >>= 1)
        v += __shfl_xor(v, off, 64);
    return v;
}

__device__ __forceinline__ float reduce32(float v) {
    #pragma unroll
    for (int off = 16; off > 0; off >>= 1)
        v += __shfl_xor(v, off, 64);
    return v;
}

// logmap0(proj(expmap0(m))) collapsed to a norm clip (one reduction).
__device__ __forceinline__ float epl_clip64(float m) {
    float n = sqrtf(wave_reduce_sum(m * m));
    float sc = (n > TCLIP) ? (TCLIP / n) : 1.0f;
    return m * sc;
}

// ---------------- kernels ----------------

// Fused build: [blocks 0..EB) ELL build, one edge per thread; [EB..):
// tangent0 = fp16(clip(x)).
#define EB ((N_EDGES + 255) / 256)
__global__ void build_kernel(const int* __restrict__ src, const int* __restrict__ dst,
                             int* __restrict__ deg, ushort* __restrict__ ell,
                             const float* __restrict__ x, __half* __restrict__ u0) {
    if (blockIdx.x < EB) {
        int e = blockIdx.x * 256 + threadIdx.x;
        if (e < N_EDGES) {
            int s = src[e];
            int d = dst[e];
            s = min(max(s, 0), N_NODES - 1);
            d = min(max(d, 0), N_NODES - 1);
            int pos = atomicAdd(&deg[d], 1);
            if (pos < ELL_CAP) ell[d * ELL_CAP + pos] = (ushort)s;
        }
    } else {
        int gid = (blockIdx.x - EB) * 256 + threadIdx.x;
        int node = gid >> 6;
        int lane = gid & 63;
        if (node >= N_NODES) return;
        float m = (lane < D_IN) ? x[node * D_IN + lane] : 0.0f;
        float t = epl_clip64(m);
        if (lane < D_IN) u0[node * D_IN + lane] = __float2half(t);
    }
}

// Repack W (f32 [K,64]) into B-fragment order for mfma_f32_16x16x32_f16.
template <int K>
__global__ void repack_kernel(const float* __restrict__ W, __half* __restrict__ Whf) {
    const int NF = K / 32;
    int idx = blockIdx.x * 256 + threadIdx.x;
    if (idx >= 4 * NF * 64 * 8) return;
    int j = idx & 7;
    int lane = (idx >> 3) & 63;
    int f = (idx >> 9) % NF;
    int jb = (idx >> 9) / NF;
    int k = f * 32 + ((lane >> 4) * 8) + j;
    int n = jb * 16 + (lane & 15);
    Whf[idx] = __float2half(W[k * 64 + n]);
}

// LAYER 1 pass A (R15): gather-mean of u0 rows (32-dim, 64B, 3.2MB table —
// fits EVERY XCD's 4MB L2 -> L2-resident gather, 1 line/edge). Full wave =
// 4 edges per load (quad q of 16 lanes handles edge base+q; lane&15 = dim
// pair). Uniform readlanes + 2 cndmasks for the quad select. Writes
// m0[N,32] fp16 (mean only; act/clip live in gemmepi after the linear —
// exact linear-after-mean swap, deg==0 handled downstream).
__global__ void meangather_kernel(const __half* __restrict__ u0, const int* __restrict__ deg,
                                  const ushort* __restrict__ ell, __half* __restrict__ m0) {
    int widx = threadIdx.x >> 6;
    int lane = threadIdx.x & 63;
    int node = blockIdx.x * 4 + widx;
    if (node >= N_NODES) return;
    int quad = lane >> 4;
    int p = lane & 15;                 // dim pair 2p, 2p+1
    int dt = deg[node];
    int d = min(dt, ELL_CAP);
    int id = (lane < d) ? (int)ell[node * ELL_CAP + lane] : 0;
    const __half2* u2 = (const __half2*)u0;   // row stride 16 half2

    float ax = 0.f, ay = 0.f;
    int e = 0;
    for (; e + 16 <= d; e += 16) {     // 16 edges, 4 loads in flight
        int sA0 = __shfl(id, e,      64), sB0 = __shfl(id, e + 1,  64);
        int sC0 = __shfl(id, e + 2,  64), sD0 = __shfl(id, e + 3,  64);
        int sA1 = __shfl(id, e + 4,  64), sB1 = __shfl(id, e + 5,  64);
        int sC1 = __shfl(id, e + 6,  64), sD1 = __shfl(id, e + 7,  64);
        int sA2 = __shfl(id, e + 8,  64), sB2 = __shfl(id, e + 9,  64);
        int sC2 = __shfl(id, e + 10, 64), sD2 = __shfl(id, e + 11, 64);
        int sA3 = __shfl(id, e + 12, 64), sB3 = __shfl(id, e + 13, 64);
        int sC3 = __shfl(id, e + 14, 64), sD3 = __shfl(id, e + 15, 64);
        int t0 = (quad & 1) ? sB0 : sA0, v0 = (quad & 1) ? sD0 : sC0;
        int t1 = (quad & 1) ? sB1 : sA1, v1 = (quad & 1) ? sD1 : sC1;
        int t2_ = (quad & 1) ? sB2 : sA2, v2 = (quad & 1) ? sD2 : sC2;
        int t3 = (quad & 1) ? sB3 : sA3, v3 = (quad & 1) ? sD3 : sC3;
        int s0 = (quad & 2) ? v0 : t0;
        int s1 = (quad & 2) ? v1 : t1;
        int s2 = (quad & 2) ? v2 : t2_;
        int s3 = (quad & 2) ? v3 : t3;
        float2 f0 = __half22float2(u2[s0 * 16 + p]);
        float2 f1 = __half22float2(u2[s1 * 16 + p]);
        float2 f2 = __half22float2(u2[s2 * 16 + p]);
        float2 f3 = __half22float2(u2[s3 * 16 + p]);
        ax += (f0.x + f1.x) + (f2.x + f3.x);
        ay += (f0.y + f1.y) + (f2.y + f3.y);
    }
    if (e + 4 <= d) {                  // 4-edge batches
        do {
            int sA = __shfl(id, e, 64), sB = __shfl(id, e + 1, 64);
            int sC = __shfl(id, e + 2, 64), sD = __shfl(id, e + 3, 64);
            int tt = (quad & 1) ? sB : sA, vv = (quad & 1) ? sD : sC;
            int s = (quad & 2) ? vv : tt;
            float2 f = __half22float2(u2[s * 16 + p]);
            ax += f.x; ay += f.y;
            e += 4;
        } while (e + 4 <= d);
    }
    for (; e < d; ++e) {               // tail: quad 0 only
        int s = __shfl(id, e, 64);
        if (quad == 0) {
            float2 f = __half22float2(u2[s * 16 + p]);
            ax += f.x; ay += f.y;
        }
    }
    // combine quads: each lane ends with the full per-dim-pair sum
    ax += __shfl_xor(ax, 16, 64); ax += __shfl_xor(ax, 32, 64);
    ay += __shfl_xor(ay, 16, 64); ay += __shfl_xor(ay, 32, 64);

    float inv = 1.0f / fmaxf((float)dt, 1.0f);
    if (quad == 0)
        ((__half2*)m0)[node * 16 + p] = __floats2half2_rn(ax * inv, ay * inv);
}

// LAYER 1 pass B (R15): u1 = clip(lrelu(m0@W1 + b1)), deg==0 -> 0.
// One wave = 16 nodes x ALL 64 cols (jb-loop over 4 MFMAs); row-norm via
// in-lane jb sum + 4 intra-quad shuffles (xor 1,2,4,8 stays in the quad).
__global__ void gemmepi_kernel(const __half* __restrict__ m0, const __half* __restrict__ Whf,
                               const float* __restrict__ b, const int* __restrict__ deg,
                               __half* __restrict__ uout) {
    int gw = blockIdx.x * 4 + (threadIdx.x >> 6);
    int lane = threadIdx.x & 63;
    int node0 = gw * 16;
    if (node0 >= N_NODES) return;
    int m = lane & 15, quad = lane >> 4;

    half8 a = *(const half8*)(m0 + (size_t)(node0 + m) * 32 + quad * 8);
    float h[4][4];   // [jb][r]
    #pragma unroll
    for (int jb = 0; jb < 4; ++jb) {
        float4v acc = {0.f, 0.f, 0.f, 0.f};
        half8 bb = ((const half8*)Whf)[jb * 64 + lane];
        acc = __builtin_amdgcn_mfma_f32_16x16x32_f16(a, bb, acc, 0, 0, 0);
        float bias = b[jb * 16 + m];
        #pragma unroll
        for (int r = 0; r < 4; ++r) h[jb][r] = acc[r] + bias;
    }
    #pragma unroll
    for (int r = 0; r < 4; ++r) {
        int node = node0 + quad * 4 + r;   // C/D: col=lane&15, row=quad*4+reg
        int dt = deg[node];
        float nr = 0.f;
        #pragma unroll
        for (int jb = 0; jb < 4; ++jb) {
            float v = (dt == 0) ? 0.f : h[jb][r];
            v = (v >= 0.f) ? v : 0.2f * v;   // leaky_relu (layer 1)
            h[jb][r] = v;
            nr += v * v;
        }
        nr += __shfl_xor(nr, 1, 64); nr += __shfl_xor(nr, 2, 64);
        nr += __shfl_xor(nr, 4, 64); nr += __shfl_xor(nr, 8, 64);
        float n = sqrtf(nr);
        float sc = (n > TCLIP) ? (TCLIP / n) : 1.0f;
        #pragma unroll
        for (int jb = 0; jb < 4; ++jb)
            uout[node * 64 + jb * 16 + m] = __float2half(h[jb][r] * sc);
    }
}

// t[N,64] fp16 = u[N,K] fp16 @ W + b via MFMA (layers 2,3).
template <int K>
__global__ void gemm_kernel(const __half* __restrict__ u, const __half* __restrict__ Whf,
                            const float* __restrict__ b, __half* __restrict__ t) {
    const int NF = K / 32;
    int gw = blockIdx.x * 4 + (threadIdx.x >> 6);
    int lane = threadIdx.x & 63;
    int jb = gw & 3;
    int tile = gw >> 2;
    int node0 = tile * 16;
    if (node0 >= N_NODES) return;
    int m = lane & 15, quad = lane >> 4;

    float4v acc = {0.f, 0.f, 0.f, 0.f};
    const half8* bfr = (const half8*)Whf + (size_t)(jb * NF) * 64 + lane;
    #pragma unroll
    for (int f = 0; f < NF; ++f) {
        half8 a = *(const half8*)(u + (size_t)(node0 + m) * K + f * 32 + quad * 8);
        half8 bb = bfr[f * 64];
        acc = __builtin_amdgcn_mfma_f32_16x16x32_f16(a, bb, acc, 0, 0, 0);
    }
    int j = jb * 16 + m;
    float bias = b[j];
    #pragma unroll
    for (int r = 0; r < 4; ++r) {
        int node = node0 + quad * 4 + r;
        t[node * 64 + j] = __float2half(acc[r] + bias);
    }
}

// Gather-mean over ELL (dual-edge half2, 8 loads in flight) -> act ->
// norm-clip epilogue -> fp16 store, or (POOL) block LDS combine + 1 atomic
// burst per block. (layers 2,3)
template <int ACT, int POOL>
__global__ void agg_kernel(const __half* __restrict__ t, const int* __restrict__ deg,
                           const ushort* __restrict__ ell, __half* __restrict__ uout,
                           const int* __restrict__ batch, float* __restrict__ pooled,
                           float* __restrict__ cntg) {
    __shared__ float rs[4][64];
    __shared__ int gs[4];
    int widx = threadIdx.x >> 6;
    int lane = threadIdx.x & 63;
    int node = blockIdx.x * 4 + widx;
    if (node >= N_NODES) return;   // never taken when POOL (50000 % 4 == 0)
    bool lo = lane < 32;
    int d2 = lane & 31;
    int dt = deg[node];
    int d = min(dt, ELL_CAP);
    int id = (lane < d) ? (int)ell[node * ELL_CAP + lane] : 0;
    const __half2* t2 = (const __half2*)t;

    float ax = 0.f, ay = 0.f;
    int e = 0;
    for (; e + 16 <= d; e += 16) {   // 16 edges, 8 wave-loads in flight
        int sA0 = __shfl(id, e,      64), sB0 = __shfl(id, e + 1,  64);
        int sA1 = __shfl(id, e + 2,  64), sB1 = __shfl(id, e + 3,  64);
        int sA2 = __shfl(id, e + 4,  64), sB2 = __shfl(id, e + 5,  64);
        int sA3 = __shfl(id, e + 6,  64), sB3 = __shfl(id, e + 7,  64);
        int sA4 = __shfl(id, e + 8,  64), sB4 = __shfl(id, e + 9,  64);
        int sA5 = __shfl(id, e + 10, 64), sB5 = __shfl(id, e + 11, 64);
        int sA6 = __shfl(id, e + 12, 64), sB6 = __shfl(id, e + 13, 64);
        int sA7 = __shfl(id, e + 14, 64), sB7 = __shfl(id, e + 15, 64);
        int s0 = lo ? sA0 : sB0;
        int s1 = lo ? sA1 : sB1;
        int s2 = lo ? sA2 : sB2;
        int s3 = lo ? sA3 : sB3;
        int s4 = lo ? sA4 : sB4;
        int s5 = lo ? sA5 : sB5;
        int s6 = lo ? sA6 : sB6;
        int s7 = lo ? sA7 : sB7;
        float2 f0 = __half22float2(t2[s0 * 32 + d2]);
        float2 f1 = __half22float2(t2[s1 * 32 + d2]);
        float2 f2 = __half22float2(t2[s2 * 32 + d2]);
        float2 f3 = __half22float2(t2[s3 * 32 + d2]);
        float2 f4 = __half22float2(t2[s4 * 32 + d2]);
        float2 f5 = __half22float2(t2[s5 * 32 + d2]);
        float2 f6 = __half22float2(t2[s6 * 32 + d2]);
        float2 f7 = __half22float2(t2[s7 * 32 + d2]);
        ax += ((f0.x + f1.x) + (f2.x + f3.x)) + ((f4.x + f5.x) + (f6.x + f7.x));
        ay += ((f0.y + f1.y) + (f2.y + f3.y)) + ((f4.y + f5.y) + (f6.y + f7.y));
    }
    if (e + 8 <= d) {
        int sA0 = __shfl(id, e,     64), sB0 = __shfl(id, e + 1, 64);
        int sA1 = __shfl(id, e + 2, 64), sB1 = __shfl(id, e + 3, 64);
        int sA2 = __shfl(id, e + 4, 64), sB2 = __shfl(id, e + 5, 64);
        int sA3 = __shfl(id, e + 6, 64), sB3 = __shfl(id, e + 7, 64);
        int s0 = lo ? sA0 : sB0;
        int s1 = lo ? sA1 : sB1;
        int s2 = lo ? sA2 : sB2;
        int s3 = lo ? sA3 : sB3;
        float2 f0 = __half22float2(t2[s0 * 32 + d2]);
        float2 f1 = __half22float2(t2[s1 * 32 + d2]);
        float2 f2 = __half22float2(t2[s2 * 32 + d2]);
        float2 f3 = __half22float2(t2[s3 * 32 + d2]);
        ax += (f0.x + f1.x) + (f2.x + f3.x);
        ay += (f0.y + f1.y) + (f2.y + f3.y);
        e += 8;
    }
    for (; e + 2 <= d; e += 2) {
        int sA = __shfl(id, e, 64), sB = __shfl(id, e + 1, 64);
        int s = lo ? sA : sB;
        float2 f = __half22float2(t2[s * 32 + d2]);
        ax += f.x; ay += f.y;
    }
    if (e < d) {
        int s = __shfl(id, e, 64);
        if (lo) {
            float2 f = __half22float2(t2[s * 32 + d2]);
            ax += f.x; ay += f.y;
        }
    }
    ax += __shfl_xor(ax, 32, 64);
    ay += __shfl_xor(ay, 32, 64);

    float inv = 1.0f / fmaxf((float)dt, 1.0f);
    float mx = ax * inv, my = ay * inv;
    if (ACT) {
        mx = (mx >= 0.f) ? mx : 0.2f * mx;
        my = (my >= 0.f) ? my : 0.2f * my;
    }
    float n = sqrtf(reduce32(mx * mx + my * my));
    float sc = (n > TCLIP) ? (TCLIP / n) : 1.0f;
    float rx = mx * sc, ry = my * sc;

    if (POOL) {
        int g = min(max(batch[node], 0), N_GRAPHS - 1);
        if (lo) { rs[widx][2 * d2] = rx; rs[widx][2 * d2 + 1] = ry; }
        if (lane == 0) gs[widx] = g;
        __syncthreads();
        int g0 = gs[0], g1 = gs[1], g2 = gs[2], g3 = gs[3];
        bool uni = (g0 == g1) && (g1 == g2) && (g2 == g3);
        if (uni) {
            if (widx == 0) {
                float sum = rs[0][lane] + rs[1][lane] + rs[2][lane] + rs[3][lane];
                atomicAdd(&pooled[g0 * 64 + lane], sum);
                if (lane == 0) atomicAdd(&cntg[g0], 4.0f);
            }
        } else {
            if (lo) {
                atomicAdd(&pooled[g * 64 + 2 * d2], rx);
                atomicAdd(&pooled[g * 64 + 2 * d2 + 1], ry);
            }
            if (lane == 0) atomicAdd(&cntg[g], 1.0f);
        }
    } else {
        if (lo) ((__half2*)uout)[node * 32 + d2] = __floats2half2_rn(rx, ry);
    }
}

// final head: mean -> clip -> @Wl + bl -> expmap0 -> proj (literal output)
__global__ void head_kernel(const float* __restrict__ pooled, const float* __restrict__ cntg,
                            const float* __restrict__ Wl, const float* __restrict__ bl,
                            float* __restrict__ out) {
    int g = blockIdx.x;
    int lane = threadIdx.x;
    float m = pooled[g * 64 + lane] / fmaxf(cntg[g], 1.0f);
    float z = epl_clip64(m);
    float acc = 0.0f;
    #pragma unroll
    for (int k = 0; k < 64; ++k) {
        float zk = __shfl(z, k, 64);
        if (lane < D_OUT) acc = fmaf(zk, Wl[k * D_OUT + lane], acc);
    }
    float o = (lane < D_OUT) ? (acc + bl[lane]) : 0.0f;
    float n = fmaxf(sqrtf(wave_reduce_sum(o * o)), EPS);
    float v = tanhf(n) * o / n;
    float nv = fmaxf(sqrtf(wave_reduce_sum(v * v)), EPS);
    if (nv > MAX_NORM) v = v * (MAX_NORM / nv);
    if (lane < D_OUT) out[g * D_OUT + lane] = v;
}

// ---------------- launch ----------------

extern "C" void kernel_launch(void* const* d_in, const int* in_sizes, int n_in,
                              void* d_out, int out_size, void* d_ws, size_t ws_size,
                              hipStream_t stream) {
    const float* x   = (const float*)d_in[0];
    const int* edge  = (const int*)d_in[1];
    const int* batch = (const int*)d_in[2];
    const float* W1  = (const float*)d_in[3];
    const float* b1  = (const float*)d_in[4];
    const float* W2  = (const float*)d_in[5];
    const float* b2  = (const float*)d_in[6];
    const float* W3  = (const float*)d_in[7];
    const float* b3  = (const float*)d_in[8];
    const float* Wl  = (const float*)d_in[9];
    const float* bl  = (const float*)d_in[10];
    float* out = (float*)d_out;

    const int N = N_NODES, E = N_EDGES, G = N_GRAPHS;
    const int* src = edge;
    const int* dst = edge + E;

    // ws layout: [deg][pooled][cntg][ell][u0h N*32][u1h N*64][u2h N*64]
    //            [th N*64][m0h N*32][Wh1][Wh2][Wh3]
    char* ws = (char*)d_ws;
    int*    deg    = (int*)ws;
    float*  pooled = (float*)(deg + N);
    float*  cntg   = pooled + (size_t)G * 64;
    ushort* ell    = (ushort*)(cntg + G);
    __half* u0h    = (__half*)(ell + (size_t)N * ELL_CAP);
    __half* u1h    = u0h + (size_t)N * 32;
    __half* u2h    = u1h + (size_t)N * 64;
    __half* th     = u2h + (size_t)N * 64;
    __half* m0h    = th + (size_t)N * 64;
    __half* Wh1    = m0h + (size_t)N * 32;    // 2048
    __half* Wh2    = Wh1 + 2048;              // 4096
    __half* Wh3    = Wh2 + 4096;              // 4096

    size_t zero_bytes = ((size_t)N + (size_t)G * 64 + G) * 4;
    hipMemsetAsync(d_ws, 0, zero_bytes, stream);

    int blocksN64 = (N * 64 + 255) / 256;   // one wave per node, 4 per block
    int blocksB   = EB + blocksN64;
    int blocksG   = 3125;                   // layers 2,3 gemm (jb split)
    int blocksT   = (3125 + 3) / 4;         // gemmepi: one wave per 16-node tile

    repack_kernel<32><<<8,  256, 0, stream>>>(W1, Wh1);
    repack_kernel<64><<<16, 256, 0, stream>>>(W2, Wh2);
    repack_kernel<64><<<16, 256, 0, stream>>>(W3, Wh3);
    build_kernel<<<blocksB, 256, 0, stream>>>(src, dst, deg, ell, x, u0h);

    // layer 1 (R15 swap): gather-mean u0 (L2-resident 3.2MB) -> MFMA+epi
    meangather_kernel<<<blocksN64, 256, 0, stream>>>(u0h, deg, ell, m0h);
    gemmepi_kernel<<<blocksT, 256, 0, stream>>>(m0h, Wh1, b1, deg, u1h);

    // layer 2
    gemm_kernel<64><<<blocksG, 256, 0, stream>>>(u1h, Wh2, b2, th);
    agg_kernel<1, 0><<<blocksN64, 256, 0, stream>>>(th, deg, ell, u2h, nullptr, nullptr, nullptr);
    // layer 3 (no act) + LDS-combined pooling
    gemm_kernel<64><<<blocksG, 256, 0, stream>>>(u2h, Wh3, b3, th);
    agg_kernel<0, 1><<<blocksN64, 256, 0, stream>>>(th, deg, ell, nullptr, batch, pooled, cntg);

    head_kernel<<<G, 64, 0, stream>>>(pooled, cntg, Wl, bl, out);
}

// Round 16
// 335.466 us; speedup vs baseline: 1.2241x; 1.0353x over previous
//
#include <hip/hip_runtime.h>
#include <hip/hip_fp16.h>
#include <hip/hip_fp8.h>
#include <math.h>

#define N_NODES 50000
#define N_EDGES 1200000
#define N_GRAPHS 128
#define D_IN 32
#define D_H 64
#define D_OUT 10
#define ELL_CAP 64

#define EPS 1e-7f
#define MAX_NORM (1.0f - 1e-5f)
// atanh(MAX_NORM): logmap0(proj(expmap0(m))) == m * min(1, TCLIP/||m||)
#define TCLIP 6.1030335f
#define T8SCALE 16.0f            // fp8 table pre-scale (folded into mean div)

typedef _Float16 half8 __attribute__((ext_vector_type(8)));
typedef float float4v __attribute__((ext_vector_type(4)));

// ---------------- wave helpers ----------------

__device__ __forceinline__ float wave_reduce_sum(float v) {
    #pragma unroll
    for (int off = 32; off > 0; off >>= 1)
        v += __shfl_xor(v, off, 64);
    return v;
}

__device__ __forceinline__ float reduce32(float v) {
    #pragma unroll
    for (int off = 16; off > 0; off >>= 1)
        v += __shfl_xor(v, off, 64);
    return v;
}

// logmap0(proj(expmap0(m))) collapsed to a norm clip (one reduction).
__device__ __forceinline__ float epl_clip64(float m) {
    float n = sqrtf(wave_reduce_sum(m * m));
    float sc = (n > TCLIP) ? (TCLIP / n) : 1.0f;
    return m * sc;
}

// two packed OCP e4m3 bytes -> two floats (gfx950 HW cvt)
__device__ __forceinline__ float2 fp8x2_to_f2(ushort v) {
    __hip_fp8_e4m3 a, b;
    a.__x = (__hip_fp8_storage_t)(v & 0xff);
    b.__x = (__hip_fp8_storage_t)(v >> 8);
    return make_float2((float)a, (float)b);
}

// ---------------- kernels ----------------

// Fused build: [blocks 0..EB) ELL build, one edge per thread; [EB..):
// tangent0 = fp16(clip(x)).
#define EB ((N_EDGES + 255) / 256)
__global__ void build_kernel(const int* __restrict__ src, const int* __restrict__ dst,
                             int* __restrict__ deg, ushort* __restrict__ ell,
                             const float* __restrict__ x, __half* __restrict__ u0) {
    if (blockIdx.x < EB) {
        int e = blockIdx.x * 256 + threadIdx.x;
        if (e < N_EDGES) {
            int s = src[e];
            int d = dst[e];
            s = min(max(s, 0), N_NODES - 1);
            d = min(max(d, 0), N_NODES - 1);
            int pos = atomicAdd(&deg[d], 1);
            if (pos < ELL_CAP) ell[d * ELL_CAP + pos] = (ushort)s;
        }
    } else {
        int gid = (blockIdx.x - EB) * 256 + threadIdx.x;
        int node = gid >> 6;
        int lane = gid & 63;
        if (node >= N_NODES) return;
        float m = (lane < D_IN) ? x[node * D_IN + lane] : 0.0f;
        float t = epl_clip64(m);
        if (lane < D_IN) u0[node * D_IN + lane] = __float2half(t);
    }
}

// Repack W (f32 [K,64]) into B-fragment order for mfma_f32_16x16x32_f16.
template <int K>
__global__ void repack_kernel(const float* __restrict__ W, __half* __restrict__ Whf) {
    const int NF = K / 32;
    int idx = blockIdx.x * 256 + threadIdx.x;
    if (idx >= 4 * NF * 64 * 8) return;
    int j = idx & 7;
    int lane = (idx >> 3) & 63;
    int f = (idx >> 9) % NF;
    int jb = (idx >> 9) / NF;
    int k = f * 32 + ((lane >> 4) * 8) + j;
    int n = jb * 16 + (lane & 15);
    Whf[idx] = __float2half(W[k * 64 + n]);
}

// LAYER 1 pass A: gather-mean of u0 rows (32-dim fp16, 64B = 1 line/edge,
// 3.2MB L2-resident). Quad-per-edge, 4 edges per wave-load.
__global__ void meangather_kernel(const __half* __restrict__ u0, const int* __restrict__ deg,
                                  const ushort* __restrict__ ell, __half* __restrict__ m0) {
    int widx = threadIdx.x >> 6;
    int lane = threadIdx.x & 63;
    int node = blockIdx.x * 4 + widx;
    if (node >= N_NODES) return;
    int quad = lane >> 4;
    int p = lane & 15;                 // dim pair 2p, 2p+1
    int dt = deg[node];
    int d = min(dt, ELL_CAP);
    int id = (lane < d) ? (int)ell[node * ELL_CAP + lane] : 0;
    const __half2* u2 = (const __half2*)u0;   // row stride 16 half2

    float ax = 0.f, ay = 0.f;
    int e = 0;
    for (; e + 16 <= d; e += 16) {     // 16 edges, 4 loads in flight
        int sA0 = __shfl(id, e,      64), sB0 = __shfl(id, e + 1,  64);
        int sC0 = __shfl(id, e + 2,  64), sD0 = __shfl(id, e + 3,  64);
        int sA1 = __shfl(id, e + 4,  64), sB1 = __shfl(id, e + 5,  64);
        int sC1 = __shfl(id, e + 6,  64), sD1 = __shfl(id, e + 7,  64);
        int sA2 = __shfl(id, e + 8,  64), sB2 = __shfl(id, e + 9,  64);
        int sC2 = __shfl(id, e + 10, 64), sD2 = __shfl(id, e + 11, 64);
        int sA3 = __shfl(id, e + 12, 64), sB3 = __shfl(id, e + 13, 64);
        int sC3 = __shfl(id, e + 14, 64), sD3 = __shfl(id, e + 15, 64);
        int t0 = (quad & 1) ? sB0 : sA0, v0 = (quad & 1) ? sD0 : sC0;
        int t1 = (quad & 1) ? sB1 : sA1, v1 = (quad & 1) ? sD1 : sC1;
        int t2_ = (quad & 1) ? sB2 : sA2, v2 = (quad & 1) ? sD2 : sC2;
        int t3 = (quad & 1) ? sB3 : sA3, v3 = (quad & 1) ? sD3 : sC3;
        int s0 = (quad & 2) ? v0 : t0;
        int s1 = (quad & 2) ? v1 : t1;
        int s2 = (quad & 2) ? v2 : t2_;
        int s3 = (quad & 2) ? v3 : t3;
        float2 f0 = __half22float2(u2[s0 * 16 + p]);
        float2 f1 = __half22float2(u2[s1 * 16 + p]);
        float2 f2 = __half22float2(u2[s2 * 16 + p]);
        float2 f3 = __half22float2(u2[s3 * 16 + p]);
        ax += (f0.x + f1.x) + (f2.x + f3.x);
        ay += (f0.y + f1.y) + (f2.y + f3.y);
    }
    if (e + 4 <= d) {
        do {
            int sA = __shfl(id, e, 64), sB = __shfl(id, e + 1, 64);
            int sC = __shfl(id, e + 2, 64), sD = __shfl(id, e + 3, 64);
            int tt = (quad & 1) ? sB : sA, vv = (quad & 1) ? sD : sC;
            int s = (quad & 2) ? vv : tt;
            float2 f = __half22float2(u2[s * 16 + p]);
            ax += f.x; ay += f.y;
            e += 4;
        } while (e + 4 <= d);
    }
    for (; e < d; ++e) {
        int s = __shfl(id, e, 64);
        if (quad == 0) {
            float2 f = __half22float2(u2[s * 16 + p]);
            ax += f.x; ay += f.y;
        }
    }
    ax += __shfl_xor(ax, 16, 64); ax += __shfl_xor(ax, 32, 64);
    ay += __shfl_xor(ay, 16, 64); ay += __shfl_xor(ay, 32, 64);

    float inv = 1.0f / fmaxf((float)dt, 1.0f);
    if (quad == 0)
        ((__half2*)m0)[node * 16 + p] = __floats2half2_rn(ax * inv, ay * inv);
}

// LAYER 1 pass B: u1 = clip(lrelu(m0@W1 + b1)), deg==0 -> 0.
__global__ void gemmepi_kernel(const __half* __restrict__ m0, const __half* __restrict__ Whf,
                               const float* __restrict__ b, const int* __restrict__ deg,
                               __half* __restrict__ uout) {
    int gw = blockIdx.x * 4 + (threadIdx.x >> 6);
    int lane = threadIdx.x & 63;
    int node0 = gw * 16;
    if (node0 >= N_NODES) return;
    int m = lane & 15, quad = lane >> 4;

    half8 a = *(const half8*)(m0 + (size_t)(node0 + m) * 32 + quad * 8);
    float h[4][4];   // [jb][r]
    #pragma unroll
    for (int jb = 0; jb < 4; ++jb) {
        float4v acc = {0.f, 0.f, 0.f, 0.f};
        half8 bb = ((const half8*)Whf)[jb * 64 + lane];
        acc = __builtin_amdgcn_mfma_f32_16x16x32_f16(a, bb, acc, 0, 0, 0);
        float bias = b[jb * 16 + m];
        #pragma unroll
        for (int r = 0; r < 4; ++r) h[jb][r] = acc[r] + bias;
    }
    #pragma unroll
    for (int r = 0; r < 4; ++r) {
        int node = node0 + quad * 4 + r;   // C/D: col=lane&15, row=quad*4+reg
        int dt = deg[node];
        float nr = 0.f;
        #pragma unroll
        for (int jb = 0; jb < 4; ++jb) {
            float v = (dt == 0) ? 0.f : h[jb][r];
            v = (v >= 0.f) ? v : 0.2f * v;   // leaky_relu (layer 1)
            h[jb][r] = v;
            nr += v * v;
        }
        nr += __shfl_xor(nr, 1, 64); nr += __shfl_xor(nr, 2, 64);
        nr += __shfl_xor(nr, 4, 64); nr += __shfl_xor(nr, 8, 64);
        float n = sqrtf(nr);
        float sc = (n > TCLIP) ? (TCLIP / n) : 1.0f;
        #pragma unroll
        for (int jb = 0; jb < 4; ++jb)
            uout[node * 64 + jb * 16 + m] = __float2half(h[jb][r] * sc);
    }
}

// t[N,64] fp8 e4m3 (x16 scale) = u[N,K] fp16 @ W + b via MFMA (layers 2,3).
// fp8 rows are 64B = ONE line per edge-gather (R16: line-request-rate model).
template <int K>
__global__ void gemm_kernel(const __half* __restrict__ u, const __half* __restrict__ Whf,
                            const float* __restrict__ b, __hip_fp8_e4m3* __restrict__ t8) {
    const int NF = K / 32;
    int gw = blockIdx.x * 4 + (threadIdx.x >> 6);
    int lane = threadIdx.x & 63;
    int jb = gw & 3;
    int tile = gw >> 2;
    int node0 = tile * 16;
    if (node0 >= N_NODES) return;
    int m = lane & 15, quad = lane >> 4;

    float4v acc = {0.f, 0.f, 0.f, 0.f};
    const half8* bfr = (const half8*)Whf + (size_t)(jb * NF) * 64 + lane;
    #pragma unroll
    for (int f = 0; f < NF; ++f) {
        half8 a = *(const half8*)(u + (size_t)(node0 + m) * K + f * 32 + quad * 8);
        half8 bb = bfr[f * 64];
        acc = __builtin_amdgcn_mfma_f32_16x16x32_f16(a, bb, acc, 0, 0, 0);
    }
    int j = jb * 16 + m;
    float bias = b[j];
    #pragma unroll
    for (int r = 0; r < 4; ++r) {
        int node = node0 + quad * 4 + r;
        t8[node * 64 + j] = __hip_fp8_e4m3((acc[r] + bias) * T8SCALE);
    }
}

// Gather-mean over ELL (fp8 rows, 64B = 1 line/edge; dual-edge pattern,
// 8 loads in flight) -> act -> norm-clip -> fp16 store, or (POOL) block
// LDS combine + 1 atomic burst per block. (layers 2,3)
template <int ACT, int POOL>
__global__ void agg_kernel(const __hip_fp8_e4m3* __restrict__ t8, const int* __restrict__ deg,
                           const ushort* __restrict__ ell, __half* __restrict__ uout,
                           const int* __restrict__ batch, float* __restrict__ pooled,
                           float* __restrict__ cntg) {
    __shared__ float rs[4][64];
    __shared__ int gs[4];
    int widx = threadIdx.x >> 6;
    int lane = threadIdx.x & 63;
    int node = blockIdx.x * 4 + widx;
    if (node >= N_NODES) return;   // never taken when POOL (50000 % 4 == 0)
    bool lo = lane < 32;
    int d2 = lane & 31;
    int dt = deg[node];
    int d = min(dt, ELL_CAP);
    int id = (lane < d) ? (int)ell[node * ELL_CAP + lane] : 0;
    const ushort* t2 = (const ushort*)t8;   // row stride 32 ushorts (64B)

    float ax = 0.f, ay = 0.f;
    int e = 0;
    for (; e + 16 <= d; e += 16) {   // 16 edges, 8 wave-loads, 16 line reqs
        int sA0 = __shfl(id, e,      64), sB0 = __shfl(id, e + 1,  64);
        int sA1 = __shfl(id, e + 2,  64), sB1 = __shfl(id, e + 3,  64);
        int sA2 = __shfl(id, e + 4,  64), sB2 = __shfl(id, e + 5,  64);
        int sA3 = __shfl(id, e + 6,  64), sB3 = __shfl(id, e + 7,  64);
        int sA4 = __shfl(id, e + 8,  64), sB4 = __shfl(id, e + 9,  64);
        int sA5 = __shfl(id, e + 10, 64), sB5 = __shfl(id, e + 11, 64);
        int sA6 = __shfl(id, e + 12, 64), sB6 = __shfl(id, e + 13, 64);
        int sA7 = __shfl(id, e + 14, 64), sB7 = __shfl(id, e + 15, 64);
        int s0 = lo ? sA0 : sB0;
        int s1 = lo ? sA1 : sB1;
        int s2 = lo ? sA2 : sB2;
        int s3 = lo ? sA3 : sB3;
        int s4 = lo ? sA4 : sB4;
        int s5 = lo ? sA5 : sB5;
        int s6 = lo ? sA6 : sB6;
        int s7 = lo ? sA7 : sB7;
        ushort w0 = t2[s0 * 32 + d2];
        ushort w1 = t2[s1 * 32 + d2];
        ushort w2 = t2[s2 * 32 + d2];
        ushort w3 = t2[s3 * 32 + d2];
        ushort w4 = t2[s4 * 32 + d2];
        ushort w5 = t2[s5 * 32 + d2];
        ushort w6 = t2[s6 * 32 + d2];
        ushort w7 = t2[s7 * 32 + d2];
        float2 f0 = fp8x2_to_f2(w0);
        float2 f1 = fp8x2_to_f2(w1);
        float2 f2 = fp8x2_to_f2(w2);
        float2 f3 = fp8x2_to_f2(w3);
        float2 f4 = fp8x2_to_f2(w4);
        float2 f5 = fp8x2_to_f2(w5);
        float2 f6 = fp8x2_to_f2(w6);
        float2 f7 = fp8x2_to_f2(w7);
        ax += ((f0.x + f1.x) + (f2.x + f3.x)) + ((f4.x + f5.x) + (f6.x + f7.x));
        ay += ((f0.y + f1.y) + (f2.y + f3.y)) + ((f4.y + f5.y) + (f6.y + f7.y));
    }
    if (e + 8 <= d) {
        int sA0 = __shfl(id, e,     64), sB0 = __shfl(id, e + 1, 64);
        int sA1 = __shfl(id, e + 2, 64), sB1 = __shfl(id, e + 3, 64);
        int sA2 = __shfl(id, e + 4, 64), sB2 = __shfl(id, e + 5, 64);
        int sA3 = __shfl(id, e + 6, 64), sB3 = __shfl(id, e + 7, 64);
        int s0 = lo ? sA0 : sB0;
        int s1 = lo ? sA1 : sB1;
        int s2 = lo ? sA2 : sB2;
        int s3 = lo ? sA3 : sB3;
        float2 f0 = fp8x2_to_f2(t2[s0 * 32 + d2]);
        float2 f1 = fp8x2_to_f2(t2[s1 * 32 + d2]);
        float2 f2 = fp8x2_to_f2(t2[s2 * 32 + d2]);
        float2 f3 = fp8x2_to_f2(t2[s3 * 32 + d2]);
        ax += (f0.x + f1.x) + (f2.x + f3.x);
        ay += (f0.y + f1.y) + (f2.y + f3.y);
        e += 8;
    }
    for (; e + 2 <= d; e += 2) {
        int sA = __shfl(id, e, 64), sB = __shfl(id, e + 1, 64);
        int s = lo ? sA : sB;
        float2 f = fp8x2_to_f2(t2[s * 32 + d2]);
        ax += f.x; ay += f.y;
    }
    if (e < d) {
        int s = __shfl(id, e, 64);
        if (lo) {
            float2 f = fp8x2_to_f2(t2[s * 32 + d2]);
            ax += f.x; ay += f.y;
        }
    }
    ax += __shfl_xor(ax, 32, 64);
    ay += __shfl_xor(ay, 32, 64);

    // mean; the /T8SCALE undoes the fp8 table pre-scale (free)
    float inv = 1.0f / (T8SCALE * fmaxf((float)dt, 1.0f));
    float mx = ax * inv, my = ay * inv;
    if (ACT) {
        mx = (mx >= 0.f) ? mx : 0.2f * mx;
        my = (my >= 0.f) ? my : 0.2f * my;
    }
    float n = sqrtf(reduce32(mx * mx + my * my));
    float sc = (n > TCLIP) ? (TCLIP / n) : 1.0f;
    float rx = mx * sc, ry = my * sc;

    if (POOL) {
        int g = min(max(batch[node], 0), N_GRAPHS - 1);
        if (lo) { rs[widx][2 * d2] = rx; rs[widx][2 * d2 + 1] = ry; }
        if (lane == 0) gs[widx] = g;
        __syncthreads();
        int g0 = gs[0], g1 = gs[1], g2 = gs[2], g3 = gs[3];
        bool uni = (g0 == g1) && (g1 == g2) && (g2 == g3);
        if (uni) {
            if (widx == 0) {
                float sum = rs[0][lane] + rs[1][lane] + rs[2][lane] + rs[3][lane];
                atomicAdd(&pooled[g0 * 64 + lane], sum);
                if (lane == 0) atomicAdd(&cntg[g0], 4.0f);
            }
        } else {
            if (lo) {
                atomicAdd(&pooled[g * 64 + 2 * d2], rx);
                atomicAdd(&pooled[g * 64 + 2 * d2 + 1], ry);
            }
            if (lane == 0) atomicAdd(&cntg[g], 1.0f);
        }
    } else {
        if (lo) ((__half2*)uout)[node * 32 + d2] = __floats2half2_rn(rx, ry);
    }
}

// final head: mean -> clip -> @Wl + bl -> expmap0 -> proj (literal output)
__global__ void head_kernel(const float* __restrict__ pooled, const float* __restrict__ cntg,
                            const float* __restrict__ Wl, const float* __restrict__ bl,
                            float* __restrict__ out) {
    int g = blockIdx.x;
    int lane = threadIdx.x;
    float m = pooled[g * 64 + lane] / fmaxf(cntg[g], 1.0f);
    float z = epl_clip64(m);
    float acc = 0.0f;
    #pragma unroll
    for (int k = 0; k < 64; ++k) {
        float zk = __shfl(z, k, 64);
        if (lane < D_OUT) acc = fmaf(zk, Wl[k * D_OUT + lane], acc);
    }
    float o = (lane < D_OUT) ? (acc + bl[lane]) : 0.0f;
    float n = fmaxf(sqrtf(wave_reduce_sum(o * o)), EPS);
    float v = tanhf(n) * o / n;
    float nv = fmaxf(sqrtf(wave_reduce_sum(v * v)), EPS);
    if (nv > MAX_NORM) v = v * (MAX_NORM / nv);
    if (lane < D_OUT) out[g * D_OUT + lane] = v;
}

// ---------------- launch ----------------

extern "C" void kernel_launch(void* const* d_in, const int* in_sizes, int n_in,
                              void* d_out, int out_size, void* d_ws, size_t ws_size,
                              hipStream_t stream) {
    const float* x   = (const float*)d_in[0];
    const int* edge  = (const int*)d_in[1];
    const int* batch = (const int*)d_in[2];
    const float* W1  = (const float*)d_in[3];
    const float* b1  = (const float*)d_in[4];
    const float* W2  = (const float*)d_in[5];
    const float* b2  = (const float*)d_in[6];
    const float* W3  = (const float*)d_in[7];
    const float* b3  = (const float*)d_in[8];
    const float* Wl  = (const float*)d_in[9];
    const float* bl  = (const float*)d_in[10];
    float* out = (float*)d_out;

    const int N = N_NODES, E = N_EDGES, G = N_GRAPHS;
    const int* src = edge;
    const int* dst = edge + E;

    // ws layout: [deg][pooled][cntg][ell][u0h N*32 h][u1h N*64 h][u2h N*64 h]
    //            [t8 N*64 fp8][m0h N*32 h][Wh1][Wh2][Wh3]
    char* ws = (char*)d_ws;
    int*    deg    = (int*)ws;
    float*  pooled = (float*)(deg + N);
    float*  cntg   = pooled + (size_t)G * 64;
    ushort* ell    = (ushort*)(cntg + G);
    __half* u0h    = (__half*)(ell + (size_t)N * ELL_CAP);
    __half* u1h    = u0h + (size_t)N * 32;
    __half* u2h    = u1h + (size_t)N * 64;
    __hip_fp8_e4m3* t8 = (__hip_fp8_e4m3*)(u2h + (size_t)N * 64);
    __half* m0h    = (__half*)((char*)t8 + (size_t)N * 64);
    __half* Wh1    = m0h + (size_t)N * 32;    // 2048
    __half* Wh2    = Wh1 + 2048;              // 4096
    __half* Wh3    = Wh2 + 4096;              // 4096

    size_t zero_bytes = ((size_t)N + (size_t)G * 64 + G) * 4;
    hipMemsetAsync(d_ws, 0, zero_bytes, stream);

    int blocksN64 = (N * 64 + 255) / 256;   // one wave per node, 4 per block
    int blocksB   = EB + blocksN64;
    int blocksG   = 3125;                   // layers 2,3 gemm (jb split)
    int blocksT   = (3125 + 3) / 4;         // gemmepi: one wave per 16-node tile

    repack_kernel<32><<<8,  256, 0, stream>>>(W1, Wh1);
    repack_kernel<64><<<16, 256, 0, stream>>>(W2, Wh2);
    repack_kernel<64><<<16, 256, 0, stream>>>(W3, Wh3);
    build_kernel<<<blocksB, 256, 0, stream>>>(src, dst, deg, ell, x, u0h);

    // layer 1: gather-mean u0 (L2-resident, 1 line/edge) -> MFMA+epi
    meangather_kernel<<<blocksN64, 256, 0, stream>>>(u0h, deg, ell, m0h);
    gemmepi_kernel<<<blocksT, 256, 0, stream>>>(m0h, Wh1, b1, deg, u1h);

    // layer 2: fp8 table (1 line/edge gather)
    gemm_kernel<64><<<blocksG, 256, 0, stream>>>(u1h, Wh2, b2, t8);
    agg_kernel<1, 0><<<blocksN64, 256, 0, stream>>>(t8, deg, ell, u2h, nullptr, nullptr, nullptr);
    // layer 3 (no act) + LDS-combined pooling
    gemm_kernel<64><<<blocksG, 256, 0, stream>>>(u2h, Wh3, b3, t8);
    agg_kernel<0, 1><<<blocksN64, 256, 0, stream>>>(t8, deg, ell, nullptr, batch, pooled, cntg);

    head_kernel<<<G, 64, 0, stream>>>(pooled, cntg, Wl, bl, out);
}